// Round 1
// baseline (585.230 us; speedup 1.0000x reference)
//
#include <hip/hip_runtime.h>

// Problem constants (must match reference)
#define NUM_PHYSICAL 2000000
#define NUM_NODES    2500000   // 2,000,000 physical + 500,000 filler
#define NBX 512
#define NBY 512

// BSX = BSY = 1000/512 = 1.953125 (exact in binary)
__device__ __constant__ const float BSX = 1.953125f;
__device__ __constant__ const float BSY = 1.953125f;
// 0.5 * BSX * sqrt(2) computed in double, rounded to f32 (matches JAX const folding)
#define HALF_STRETCH_X ((float)(0.5 * 1.953125 * 1.4142135623730951))
#define HALF_STRETCH_Y ((float)(0.5 * 1.953125 * 1.4142135623730951))
// BSX*BSY*UNIT_PIN_CAPACITY = 61.03515625 (exact)
#define NORM_DIV 61.03515625f
#define MAX_RATE 2.5f
#define MIN_RATE 0.4f   // 1/2.5 exactly

__global__ void zero_acc_kernel(float* __restrict__ acc, int n) {
    int i = blockIdx.x * blockDim.x + threadIdx.x;
    if (i < n) acc[i] = 0.0f;
}

__global__ __launch_bounds__(256) void pin_scatter_kernel(
        const float* __restrict__ pos,        // [2*NUM_NODES]: x then y
        const float* __restrict__ node_size_x,
        const float* __restrict__ node_size_y,
        const float* __restrict__ pin_weights,
        float* __restrict__ acc)              // [NBX*NBY] raw sums
{
    int i = blockIdx.x * blockDim.x + threadIdx.x;
    if (i >= NUM_PHYSICAL) return;

    float sx = node_size_x[i];
    float sy = node_size_y[i];
    // hx = 0.5 * max(sx, BSX*sqrt2)
    float hx = 0.5f * fmaxf(sx, 2.0f * HALF_STRETCH_X);
    float hy = 0.5f * fmaxf(sy, 2.0f * HALF_STRETCH_Y);
    float cx = pos[i]             + 0.5f * sx;
    float cy = pos[NUM_NODES + i] + 0.5f * sy;
    float x_min = cx - hx, x_max = cx + hx;
    float y_min = cy - hy, y_max = cy + hy;
    float density = pin_weights[i] / (4.0f * hx * hy);

    int bxl = (int)floorf(x_min / BSX);
    int byl = (int)floorf(y_min / BSY);

    // Span 2*hx <= 3 < 2*BSX => at most 3 bins per axis overlap; the
    // reference's kx=3/ky=3 iterations always fail the ox>0/oy>0 mask.
    #pragma unroll
    for (int kx = 0; kx < 3; ++kx) {
        int ix = bxl + kx;
        float bx_lo = (float)ix * BSX;
        float ox = fminf(x_max, bx_lo + BSX) - fmaxf(x_min, bx_lo);
        if (ix < 0 || ix >= NBX || !(ox > 0.0f)) continue;
        #pragma unroll
        for (int ky = 0; ky < 3; ++ky) {
            int iy = byl + ky;
            float by_lo = (float)iy * BSY;
            float oy = fminf(y_max, by_lo + BSY) - fmaxf(y_min, by_lo);
            if (iy >= 0 && iy < NBY && oy > 0.0f) {
                atomicAdd(&acc[ix * NBY + iy], ox * oy * density);
            }
        }
    }
}

__global__ void finalize_kernel(float* __restrict__ out, int n) {
    int i = blockIdx.x * blockDim.x + threadIdx.x;
    if (i < n) {
        float u = out[i] / NORM_DIV;
        u = fminf(fmaxf(u, MIN_RATE), MAX_RATE);
        out[i] = u;
    }
}

extern "C" void kernel_launch(void* const* d_in, const int* in_sizes, int n_in,
                              void* d_out, int out_size, void* d_ws, size_t ws_size,
                              hipStream_t stream) {
    const float* pos          = (const float*)d_in[0];
    const float* node_size_x  = (const float*)d_in[1];
    const float* node_size_y  = (const float*)d_in[2];
    const float* pin_weights  = (const float*)d_in[3];
    float* out = (float*)d_out;

    const int nbins = NBX * NBY;  // == out_size (262144)

    // 1) zero the accumulator (d_out doubles as the raw-sum buffer);
    //    must happen every launch since graph replays don't re-poison.
    zero_acc_kernel<<<(nbins + 255) / 256, 256, 0, stream>>>(out, nbins);

    // 2) scatter-add
    pin_scatter_kernel<<<(NUM_PHYSICAL + 255) / 256, 256, 0, stream>>>(
        pos, node_size_x, node_size_y, pin_weights, out);

    // 3) scale + clip in place
    finalize_kernel<<<(nbins + 255) / 256, 256, 0, stream>>>(out, nbins);
}

// Round 2
// 584.548 us; speedup vs baseline: 1.0012x; 1.0012x over previous
//
#include <hip/hip_runtime.h>

// Problem constants (must match reference)
#define NUM_PHYSICAL 2000000
#define NUM_NODES    2500000   // 2,000,000 physical + 500,000 filler
#define NBX 512
#define NBY 512

// BSX = BSY = 1000/512 = 1.953125 (exact in binary)
#define BSX 1.953125f
#define BSY 1.953125f
// 0.5 * BSX * sqrt(2) computed in double, rounded to f32 (matches JAX const folding)
#define HALF_STRETCH_X ((float)(0.5 * 1.953125 * 1.4142135623730951))
#define HALF_STRETCH_Y ((float)(0.5 * 1.953125 * 1.4142135623730951))
// BSX*BSY*UNIT_PIN_CAPACITY = 61.03515625 (exact)
#define NORM_DIV 61.03515625f
#define MAX_RATE 2.5f
#define MIN_RATE 0.4f   // 1/2.5 exactly

// Hardware float atomic (global_atomic_add_f32), bypassing the compiler's
// conservative CAS-loop lowering of atomicAdd(float*).
__device__ __forceinline__ void hw_atomic_add(float* addr, float val) {
#if defined(__HIP_DEVICE_COMPILE__)
    unsafeAtomicAdd(addr, val);
#else
    atomicAdd(addr, val);
#endif
}

__global__ void zero_acc_kernel(float* __restrict__ acc, int n) {
    int i = blockIdx.x * blockDim.x + threadIdx.x;
    if (i < n) acc[i] = 0.0f;
}

__global__ __launch_bounds__(256) void pin_scatter_kernel(
        const float* __restrict__ pos,        // [2*NUM_NODES]: x then y
        const float* __restrict__ node_size_x,
        const float* __restrict__ node_size_y,
        const float* __restrict__ pin_weights,
        float* __restrict__ acc)              // [NBX*NBY] raw sums
{
    int i = blockIdx.x * blockDim.x + threadIdx.x;
    if (i >= NUM_PHYSICAL) return;

    float sx = node_size_x[i];
    float sy = node_size_y[i];
    // hx = 0.5 * max(sx, BSX*sqrt2)
    float hx = 0.5f * fmaxf(sx, 2.0f * HALF_STRETCH_X);
    float hy = 0.5f * fmaxf(sy, 2.0f * HALF_STRETCH_Y);
    float cx = pos[i]             + 0.5f * sx;
    float cy = pos[NUM_NODES + i] + 0.5f * sy;
    float x_min = cx - hx, x_max = cx + hx;
    float y_min = cy - hy, y_max = cy + hy;
    float density = pin_weights[i] / (4.0f * hx * hy);

    int bxl = (int)floorf(x_min / BSX);
    int byl = (int)floorf(y_min / BSY);

    // Span 2*hx <= 3 < 2*BSX => at most 3 bins per axis overlap; the
    // reference's kx=3/ky=3 iterations always fail the ox>0/oy>0 mask.
    #pragma unroll
    for (int kx = 0; kx < 3; ++kx) {
        int ix = bxl + kx;
        float bx_lo = (float)ix * BSX;
        float ox = fminf(x_max, bx_lo + BSX) - fmaxf(x_min, bx_lo);
        if (ix < 0 || ix >= NBX || !(ox > 0.0f)) continue;
        #pragma unroll
        for (int ky = 0; ky < 3; ++ky) {
            int iy = byl + ky;
            float by_lo = (float)iy * BSY;
            float oy = fminf(y_max, by_lo + BSY) - fmaxf(y_min, by_lo);
            if (iy >= 0 && iy < NBY && oy > 0.0f) {
                hw_atomic_add(&acc[ix * NBY + iy], ox * oy * density);
            }
        }
    }
}

__global__ void finalize_kernel(float* __restrict__ out, int n) {
    int i = blockIdx.x * blockDim.x + threadIdx.x;
    if (i < n) {
        float u = out[i] / NORM_DIV;
        u = fminf(fmaxf(u, MIN_RATE), MAX_RATE);
        out[i] = u;
    }
}

extern "C" void kernel_launch(void* const* d_in, const int* in_sizes, int n_in,
                              void* d_out, int out_size, void* d_ws, size_t ws_size,
                              hipStream_t stream) {
    const float* pos          = (const float*)d_in[0];
    const float* node_size_x  = (const float*)d_in[1];
    const float* node_size_y  = (const float*)d_in[2];
    const float* pin_weights  = (const float*)d_in[3];
    float* out = (float*)d_out;

    const int nbins = NBX * NBY;  // == out_size (262144)

    // 1) zero the accumulator (d_out doubles as the raw-sum buffer);
    //    must happen every launch since graph replays don't re-poison.
    zero_acc_kernel<<<(nbins + 255) / 256, 256, 0, stream>>>(out, nbins);

    // 2) scatter-add
    pin_scatter_kernel<<<(NUM_PHYSICAL + 255) / 256, 256, 0, stream>>>(
        pos, node_size_x, node_size_y, pin_weights, out);

    // 3) scale + clip in place
    finalize_kernel<<<(nbins + 255) / 256, 256, 0, stream>>>(out, nbins);
}